// Round 9
// baseline (275.974 us; speedup 1.0000x reference)
//
#include <hip/hip_runtime.h>
#include <cmath>

typedef __attribute__((ext_vector_type(8))) short short8;
typedef __attribute__((ext_vector_type(4))) float floatx4;

#define T_TOK 32768
#define DIMK 512

__device__ __forceinline__ unsigned short f2bf(float f) {
  union { float f; unsigned int u; } v; v.f = f;
  unsigned int r = (v.u + 0x7fffu + ((v.u >> 16) & 1u)) >> 16;
  return (unsigned short)r;
}
__device__ __forceinline__ float bf2f(unsigned short h) {
  union { unsigned int u; float f; } v; v.u = ((unsigned int)h) << 16;
  return v.f;
}

// async global->LDS 16B per lane: HW writes lane i at ldsbase + i*16
__device__ __forceinline__ void gload_lds16(const unsigned short* g, unsigned short* ldsbase) {
  __builtin_amdgcn_global_load_lds(
      (const __attribute__((address_space(1))) unsigned int*)g,
      (__attribute__((address_space(3))) unsigned int*)ldsbase, 16, 0, 0);
}

// ------- prep: [blocks 0..2047] weights->bf16 + rope + zero; [2048..4095] rmsnorm -------
// rmsnorm batched 4 tokens/wave (r8-verified).
__global__ __launch_bounds__(256) void k_prep(const float* __restrict__ x,
    const float* __restrict__ norm_w, const float* __restrict__ wq,
    const float* __restrict__ wk, const float* __restrict__ wv,
    const float* __restrict__ wo, unsigned short* __restrict__ Wb,
    unsigned short* __restrict__ wob, float2* __restrict__ rope,
    float* __restrict__ KVz, unsigned short* __restrict__ xn) {
  if (blockIdx.x < 2048) {
    int i = blockIdx.x * 256 + threadIdx.x;  // 524288
    float v;
    if (i < 262144) {
      v = wq[i];
    } else {
      int R = i >> 9, col = i & 511;
      int h = (R - 512) >> 7, rem = (R - 512) & 127;
      if (rem < 64) v = wk[(h * 64 + rem) * 512 + col];
      else          v = wv[(h * 64 + rem - 64) * 512 + col];
    }
    Wb[i] = f2bf(v);
    if (i < 262144) {
      wob[i] = f2bf(wo[i]);
      int s = i >> 5, m = i & 31;
      const double c0 = 0.74989420933245582;   // 10^(-1/8)
      double c1 = c0 * c0, c2 = c1 * c1, c3 = c2 * c2, c4 = c3 * c3;
      double p = 1.0;
      if (m & 1)  p *= c0;
      if (m & 2)  p *= c1;
      if (m & 4)  p *= c2;
      if (m & 8)  p *= c3;
      if (m & 16) p *= c4;
      double ang = (double)s * p;
      const double TWO_PI = 6.2831853071795864769;
      double q = rint(ang * (1.0 / TWO_PI));
      double r = fma(-q, TWO_PI, ang);
      float rf = (float)r;
      rope[i] = make_float2(cosf(rf), sinf(rf));
    }
    if (i < 2048) KVz[i] = 0.f;   // zero KV (1024 f32) + Ksum (1024 f32)
  } else {
    // rmsnorm: 2048 blocks x 4 waves x 4 tokens
    int bid = blockIdx.x - 2048;
    int wave = threadIdx.x >> 6, lane = threadIdx.x & 63;
    size_t t0 = ((size_t)bid * 4 + wave) * 4;
    const float4* wr = (const float4*)norm_w;
    float4 w0 = wr[lane * 2], w1 = wr[lane * 2 + 1];
    float4 a[4], b[4];
    #pragma unroll
    for (int j = 0; j < 4; j++) {
      const float4* xr = (const float4*)(x + (t0 + j) * DIMK);
      a[j] = xr[lane * 2];
      b[j] = xr[lane * 2 + 1];
    }
    #pragma unroll
    for (int j = 0; j < 4; j++) {
      float ss = a[j].x * a[j].x + a[j].y * a[j].y + a[j].z * a[j].z + a[j].w * a[j].w
               + b[j].x * b[j].x + b[j].y * b[j].y + b[j].z * b[j].z + b[j].w * b[j].w;
      #pragma unroll
      for (int off = 32; off >= 1; off >>= 1) ss += __shfl_xor(ss, off, 64);
      float scale = rsqrtf(ss * (1.0f / DIMK) + 1e-6f);
      uint4 o;
      o.x = (unsigned int)f2bf(a[j].x * scale * w0.x) | ((unsigned int)f2bf(a[j].y * scale * w0.y) << 16);
      o.y = (unsigned int)f2bf(a[j].z * scale * w0.z) | ((unsigned int)f2bf(a[j].w * scale * w0.w) << 16);
      o.z = (unsigned int)f2bf(b[j].x * scale * w1.x) | ((unsigned int)f2bf(b[j].y * scale * w1.y) << 16);
      o.w = (unsigned int)f2bf(b[j].z * scale * w1.z) | ((unsigned int)f2bf(b[j].w * scale * w1.w) << 16);
      *(uint4*)(xn + (t0 + j) * DIMK + lane * 8) = o;
    }
  }
}

// ------- GEMM1: qkv_Q(M,512) = xn(M,512) * Wb(1024,512)^T (Q part written; K/V fused) -------
// 256x256 tile, BK=64, 8 waves, 8-phase counted-vmcnt schedule + setprio (r2-verified).
// FUSE (r4-verified + r5 bank rotation): n0>=512 tiles hold interleaved K|V
// columns; epilogue does rope+phi on K, multiplies V from LDS, atomic KV/Ksum.
template <bool BF16_OUT, bool FUSE>
__global__ __launch_bounds__(512, 2) void k_gemm256(const unsigned short* __restrict__ A,
    const unsigned short* __restrict__ Bw, void* __restrict__ Cv, int ldc,
    const float2* __restrict__ rope, float* __restrict__ KV, float* __restrict__ Ksum) {
  constexpr int K = DIMK;
  extern __shared__ __align__(16) unsigned short smem[];
  unsigned short* const AsP = smem;            // [2][16384] shorts (64 KiB)
  unsigned short* const BsP = smem + 32768;    // [2][16384] shorts (64 KiB)

  const int tid = threadIdx.x;
  const int wave = tid >> 6, lane = tid & 63;
  const int r = lane & 15, quad = lane >> 4, r7 = r & 7;
  const int wm = (wave >> 2) * 128, wn = (wave & 3) * 64;

  const int nwg = gridDim.x * gridDim.y;
  const int bid = blockIdx.x + gridDim.x * blockIdx.y;
  const int cpx = nwg >> 3;
  const int nid = (bid & 7) * cpx + (bid >> 3);
  const int m0 = (nid & 127) * 256;   // gridDim.x == 128 always here
  const int n0 = (nid >> 7) * 256;

  const int srow = lane >> 3;
  const int scb = (lane & 7) ^ srow;
  const unsigned short* const Asrc = A + (size_t)(m0 + wave * 8 + srow) * K + scb * 8;
  const unsigned short* const Bsrc = Bw + (size_t)(n0 + wave * 8 + srow) * K + scb * 8;
  unsigned short* const Adst = AsP + wave * 8 * 64;
  unsigned short* const Bdst = BsP + wave * 8 * 64;

#define STAGE_A(buf, h, kt) do { \
    gload_lds16(Asrc + (size_t)((h) * 128) * K + (kt) * 64, Adst + (buf) * 16384 + ((h) * 128) * 64); \
    gload_lds16(Asrc + (size_t)((h) * 128 + 64) * K + (kt) * 64, Adst + (buf) * 16384 + ((h) * 128 + 64) * 64); \
  } while (0)
#define STAGE_B(buf, h, kt) do { \
    gload_lds16(Bsrc + (size_t)((h) * 128) * K + (kt) * 64, Bdst + (buf) * 16384 + ((h) * 128) * 64); \
    gload_lds16(Bsrc + (size_t)((h) * 128 + 64) * K + (kt) * 64, Bdst + (buf) * 16384 + ((h) * 128 + 64) * 64); \
  } while (0)

  short8 af[4][2], b0[2][2], b1[2][2];
  floatx4 acc[8][4];
  #pragma unroll
  for (int i = 0; i < 8; i++)
    #pragma unroll
    for (int jj = 0; jj < 4; jj++)
      acc[i][jj] = (floatx4){0.f, 0.f, 0.f, 0.f};

#define LDA8(buf, ah) do { \
    _Pragma("unroll") for (int ii = 0; ii < 4; ii++) \
      _Pragma("unroll") for (int kk = 0; kk < 2; kk++) \
        af[ii][kk] = *(const short8*)&AsP[(buf) * 16384 + (wm + (ah) * 64 + ii * 16 + r) * 64 + ((kk * 4 + quad) ^ r7) * 8]; \
  } while (0)
#define LDB4(buf, bh, arr) do { \
    _Pragma("unroll") for (int jj = 0; jj < 2; jj++) \
      _Pragma("unroll") for (int kk = 0; kk < 2; kk++) \
        arr[jj][kk] = *(const short8*)&BsP[(buf) * 16384 + (wn + (bh) * 32 + jj * 16 + r) * 64 + ((kk * 4 + quad) ^ r7) * 8]; \
  } while (0)
#define MFMAQ(ah, bh, arr) do { \
    __builtin_amdgcn_s_setprio(1); \
    _Pragma("unroll") for (int ii = 0; ii < 4; ii++) \
      _Pragma("unroll") for (int jj = 0; jj < 2; jj++) \
        _Pragma("unroll") for (int kk = 0; kk < 2; kk++) \
          acc[(ah) * 4 + ii][(bh) * 2 + jj] = __builtin_amdgcn_mfma_f32_16x16x32_bf16( \
              af[ii][kk], arr[jj][kk], acc[(ah) * 4 + ii][(bh) * 2 + jj], 0, 0, 0); \
    __builtin_amdgcn_s_setprio(0); \
  } while (0)
#define BAR() do { asm volatile("" ::: "memory"); __builtin_amdgcn_s_barrier(); asm volatile("" ::: "memory"); } while (0)
#define VMW(n) do { asm volatile("s_waitcnt vmcnt(" #n ")" ::: "memory"); __builtin_amdgcn_sched_barrier(0); } while (0)

  STAGE_A(0, 0, 0); STAGE_B(0, 0, 0); STAGE_A(0, 1, 0); STAGE_B(0, 1, 0);
  STAGE_A(1, 0, 1); STAGE_B(1, 0, 1); STAGE_A(1, 1, 1); STAGE_B(1, 1, 1);
  VMW(8);
  BAR();

  #pragma unroll
  for (int it = 0; it < 3; ++it) {
    const int kt = it * 2;
    LDA8(0, 0); LDB4(0, 0, b0);
    BAR(); MFMAQ(0, 0, b0); BAR();
    LDB4(0, 1, b1);
    BAR(); MFMAQ(0, 1, b1); BAR();
    LDA8(0, 1); STAGE_B(0, 0, kt + 2); STAGE_B(0, 1, kt + 2);
    BAR(); MFMAQ(1, 1, b1); BAR();
    STAGE_A(0, 0, kt + 2); STAGE_A(0, 1, kt + 2);
    BAR(); MFMAQ(1, 0, b0); VMW(8); BAR();
    LDA8(1, 0); LDB4(1, 0, b0);
    BAR(); MFMAQ(0, 0, b0); BAR();
    LDB4(1, 1, b1);
    BAR(); MFMAQ(0, 1, b1); BAR();
    LDA8(1, 1); STAGE_B(1, 0, kt + 3); STAGE_B(1, 1, kt + 3);
    BAR(); MFMAQ(1, 1, b1); BAR();
    STAGE_A(1, 0, kt + 3); STAGE_A(1, 1, kt + 3);
    BAR(); MFMAQ(1, 0, b0); VMW(8); BAR();
  }

  LDA8(0, 0); LDB4(0, 0, b0);
  BAR(); MFMAQ(0, 0, b0); BAR();
  LDB4(0, 1, b1);
  BAR(); MFMAQ(0, 1, b1); BAR();
  LDA8(0, 1);
  BAR(); MFMAQ(1, 1, b1); BAR();
  MFMAQ(1, 0, b0); VMW(0); BAR();
  LDA8(1, 0); LDB4(1, 0, b0);
  BAR(); MFMAQ(0, 0, b0); BAR();
  LDB4(1, 1, b1);
  BAR(); MFMAQ(0, 1, b1); BAR();
  LDA8(1, 1);
  BAR(); MFMAQ(1, 1, b1); BAR();
  MFMAQ(1, 0, b0);

  if (FUSE && n0 >= 512) {
#define VSW(t, d) ((t) * 128 + ((d) & 15) + (((((d) >> 4) + ((t) >> 2)) & 7) << 4))
    const int b = m0 >> 13;
    const int kh = ((n0 - 512) >> 8) * 2 + (wn >> 7);   // n-tile is 256 wide
    const int hvb = (wn >> 7) << 6;            // V col base in Vs (0 or 64)
    float* const Vs = (float*)smem;            // [256][128] f32 = 128 KiB
    __syncthreads();
    if (wn & 64) {                             // V-wave: dump acc to LDS
      #pragma unroll
      for (int i = 0; i < 8; i++)
        #pragma unroll
        for (int j2 = 0; j2 < 4; j2++)
          #pragma unroll
          for (int p = 0; p < 4; p++) {
            int t = wm + i * 16 + quad * 4 + p;
            Vs[VSW(t, hvb + j2 * 16 + r)] = acc[i][j2][p];
          }
    }
    __syncthreads();
    if (!(wn & 64)) {                          // K-wave: rope+phi, mul V, reduce
      float kvp[4] = {0.f, 0.f, 0.f, 0.f};
      float ksp[4] = {0.f, 0.f, 0.f, 0.f};
      #pragma unroll
      for (int i = 0; i < 8; i++)
        #pragma unroll
        for (int p = 0; p < 4; p++) {
          int t = wm + i * 16 + quad * 4 + p;
          int pos = (m0 + t) & 8191;
          #pragma unroll
          for (int j2 = 0; j2 < 4; j2++) {
            float v = acc[i][j2][p];
            float vp = __shfl_xor(v, 1, 64);
            int d = j2 * 16 + r;
            float2 cs = rope[pos * 32 + (d >> 1)];
            float rk = (r & 1) ? (vp * cs.y + v * cs.x) : (v * cs.x - vp * cs.y);
            rk = rk > 0.f ? rk + 1.f : __expf(rk);
            kvp[j2] += rk * Vs[VSW(t, hvb + d)];
            ksp[j2] += rk;
          }
        }
      #pragma unroll
      for (int j2 = 0; j2 < 4; j2++) {
        kvp[j2] += __shfl_xor(kvp[j2], 16, 64); kvp[j2] += __shfl_xor(kvp[j2], 32, 64);
        ksp[j2] += __shfl_xor(ksp[j2], 16, 64); ksp[j2] += __shfl_xor(ksp[j2], 32, 64);
      }
      if (lane < 16) {
        int base = (b * 4 + kh) * 64 + r;
        #pragma unroll
        for (int j2 = 0; j2 < 4; j2++) {
          atomicAdd(&KV[base + j2 * 16], kvp[j2]);
          atomicAdd(&Ksum[base + j2 * 16], ksp[j2]);
        }
      }
    }
#undef VSW
  } else {
    #pragma unroll
    for (int i = 0; i < 8; i++)
      #pragma unroll
      for (int j2 = 0; j2 < 4; j2++) {
        int row = m0 + wm + i * 16 + quad * 4;
        int col = n0 + wn + j2 * 16 + r;
        #pragma unroll
        for (int p = 0; p < 4; p++) {
          if constexpr (BF16_OUT) {
            ((unsigned short*)Cv)[(size_t)(row + p) * ldc + col] = f2bf(acc[i][j2][p]);
          } else {
            ((float*)Cv)[(size_t)(row + p) * ldc + col] = acc[i][j2][p];
          }
        }
      }
  }
#undef STAGE_A
#undef STAGE_B
#undef LDA8
#undef LDB4
#undef MFMAQ
#undef BAR
#undef VMW
}

// ------- GEMM2 with fused Q-finish: out(M,512) = Y(M,512) * wob(512,512)^T -------
// Y is NOT materialized: A-staging reg-loads qkv (Q projection), applies
// rope (per-lane rope regs preloaded once -- rows are kt-invariant), phi,
// Z via 3 shfl_xor over the 8-lane row group, scales by KV/(Z+eps), f2bf,
// ds_write_b128 to the SAME swizzled LDS slot the template uses (c^srow).
// B keeps gload_lds; counted vmcnt re-derived for B-only: VMW(4) at P4/P8.
// ds_write publication: explicit lgkmcnt(0)+sched_barrier before the barrier.
__global__ __launch_bounds__(512, 2) void k_gemm2q(const unsigned short* __restrict__ Aq,
    const unsigned short* __restrict__ Bw, float* __restrict__ Cv,
    const float* __restrict__ ropef, const float* __restrict__ KV,
    const float* __restrict__ Ksum) {
  constexpr int K = DIMK;
  extern __shared__ __align__(16) unsigned short smem[];
  unsigned short* const AsP = smem;            // [2][16384] shorts (64 KiB)
  unsigned short* const BsP = smem + 32768;    // [2][16384] shorts (64 KiB)

  const int tid = threadIdx.x;
  const int wave = tid >> 6, lane = tid & 63;
  const int r = lane & 15, quad = lane >> 4, r7 = r & 7;
  const int wm = (wave >> 2) * 128, wn = (wave & 3) * 64;
  const int srow = lane >> 3, cc = lane & 7;
  const int scb = cc ^ srow;

  const int nwg = gridDim.x * gridDim.y;       // 256
  const int bid = blockIdx.x + gridDim.x * blockIdx.y;
  const int cpx = nwg >> 3;
  const int nid = (bid & 7) * cpx + (bid >> 3);
  const int m0 = (nid & 127) * 256;
  const int n0 = (nid >> 7) * 256;
  const int bq = m0 >> 13;                     // batch
  const int d0 = cc * 8;                       // this lane's 8 dims within a head

  const unsigned short* const Bsrc = Bw + (size_t)(n0 + wave * 8 + srow) * K + scb * 8;
  unsigned short* const Bdst = BsP + wave * 8 * 64;

#define BSTG(buf, kt) do { \
    gload_lds16(Bsrc + (size_t)0 * K + (kt) * 64, Bdst + (buf) * 16384 + 0 * 64); \
    gload_lds16(Bsrc + (size_t)64 * K + (kt) * 64, Bdst + (buf) * 16384 + 64 * 64); \
    gload_lds16(Bsrc + (size_t)128 * K + (kt) * 64, Bdst + (buf) * 16384 + 128 * 64); \
    gload_lds16(Bsrc + (size_t)192 * K + (kt) * 64, Bdst + (buf) * 16384 + 192 * 64); \
  } while (0)

  // per-lane persistent rope regs: 4 rows (kt-invariant), 2 float4 each
  float4 rp[8];
  uint4 qreg[4];
  float4 kvA, kvB, ksA, ksB;
  #pragma unroll
  for (int ss = 0; ss < 4; ss++) {
    int R = (ss >> 1) * 128 + (ss & 1) * 64 + wave * 8 + srow;
    int pos = (m0 + R) & 8191;
    rp[ss * 2]     = *(const float4*)(ropef + (size_t)pos * 64 + cc * 8);
    rp[ss * 2 + 1] = *(const float4*)(ropef + (size_t)pos * 64 + cc * 8 + 4);
  }

#define QLOAD(kt) do { \
    const int bk_ = bq * 4 + ((kt) >> 1); \
    kvA = *(const float4*)(KV + bk_ * 64 + d0); \
    kvB = *(const float4*)(KV + bk_ * 64 + d0 + 4); \
    ksA = *(const float4*)(Ksum + bk_ * 64 + d0); \
    ksB = *(const float4*)(Ksum + bk_ * 64 + d0 + 4); \
    _Pragma("unroll") for (int ss = 0; ss < 4; ss++) { \
      int R_ = (ss >> 1) * 128 + (ss & 1) * 64 + wave * 8 + srow; \
      qreg[ss] = *(const uint4*)(Aq + (size_t)(m0 + R_) * 512 + (kt) * 64 + d0); \
    } \
  } while (0)

#define PH(x) ((x) > 0.f ? (x) + 1.f : __expf(x))

#define QWRITE(buf) do { \
    _Pragma("unroll") for (int ss = 0; ss < 4; ss++) { \
      int R_ = (ss >> 1) * 128 + (ss & 1) * 64 + wave * 8 + srow; \
      float q0 = bf2f((unsigned short)(qreg[ss].x & 0xffffu)); \
      float q1 = bf2f((unsigned short)(qreg[ss].x >> 16)); \
      float q2 = bf2f((unsigned short)(qreg[ss].y & 0xffffu)); \
      float q3 = bf2f((unsigned short)(qreg[ss].y >> 16)); \
      float q4 = bf2f((unsigned short)(qreg[ss].z & 0xffffu)); \
      float q5 = bf2f((unsigned short)(qreg[ss].z >> 16)); \
      float q6 = bf2f((unsigned short)(qreg[ss].w & 0xffffu)); \
      float q7 = bf2f((unsigned short)(qreg[ss].w >> 16)); \
      float4 ra = rp[ss * 2], rb = rp[ss * 2 + 1]; \
      float p0 = PH(q0 * ra.x - q1 * ra.y), p1 = PH(q0 * ra.y + q1 * ra.x); \
      float p2 = PH(q2 * ra.z - q3 * ra.w), p3 = PH(q2 * ra.w + q3 * ra.z); \
      float p4 = PH(q4 * rb.x - q5 * rb.y), p5 = PH(q4 * rb.y + q5 * rb.x); \
      float p6 = PH(q6 * rb.z - q7 * rb.w), p7 = PH(q6 * rb.w + q7 * rb.z); \
      float zp = p0 * ksA.x + p1 * ksA.y + p2 * ksA.z + p3 * ksA.w \
               + p4 * ksB.x + p5 * ksB.y + p6 * ksB.z + p7 * ksB.w; \
      zp += __shfl_xor(zp, 1, 64); \
      zp += __shfl_xor(zp, 2, 64); \
      zp += __shfl_xor(zp, 4, 64); \
      float inv_ = 1.0f / (zp + 1e-6f); \
      uint4 o_; \
      o_.x = (unsigned int)f2bf(p0 * kvA.x * inv_) | ((unsigned int)f2bf(p1 * kvA.y * inv_) << 16); \
      o_.y = (unsigned int)f2bf(p2 * kvA.z * inv_) | ((unsigned int)f2bf(p3 * kvA.w * inv_) << 16); \
      o_.z = (unsigned int)f2bf(p4 * kvB.x * inv_) | ((unsigned int)f2bf(p5 * kvB.y * inv_) << 16); \
      o_.w = (unsigned int)f2bf(p6 * kvB.z * inv_) | ((unsigned int)f2bf(p7 * kvB.w * inv_) << 16); \
      *(uint4*)&AsP[(buf) * 16384 + R_ * 64 + (cc ^ srow) * 8] = o_; \
    } \
  } while (0)

  short8 af[4][2], b0[2][2], b1[2][2];
  floatx4 acc[8][4];
  #pragma unroll
  for (int i = 0; i < 8; i++)
    #pragma unroll
    for (int jj = 0; jj < 4; jj++)
      acc[i][jj] = (floatx4){0.f, 0.f, 0.f, 0.f};

#define LDA8(buf, ah) do { \
    _Pragma("unroll") for (int ii = 0; ii < 4; ii++) \
      _Pragma("unroll") for (int kk = 0; kk < 2; kk++) \
        af[ii][kk] = *(const short8*)&AsP[(buf) * 16384 + (wm + (ah) * 64 + ii * 16 + r) * 64 + ((kk * 4 + quad) ^ r7) * 8]; \
  } while (0)
#define LDB4(buf, bh, arr) do { \
    _Pragma("unroll") for (int jj = 0; jj < 2; jj++) \
      _Pragma("unroll") for (int kk = 0; kk < 2; kk++) \
        arr[jj][kk] = *(const short8*)&BsP[(buf) * 16384 + (wn + (bh) * 32 + jj * 16 + r) * 64 + ((kk * 4 + quad) ^ r7) * 8]; \
  } while (0)
#define MFMAQ(ah, bh, arr) do { \
    __builtin_amdgcn_s_setprio(1); \
    _Pragma("unroll") for (int ii = 0; ii < 4; ii++) \
      _Pragma("unroll") for (int jj = 0; jj < 2; jj++) \
        _Pragma("unroll") for (int kk = 0; kk < 2; kk++) \
          acc[(ah) * 4 + ii][(bh) * 2 + jj] = __builtin_amdgcn_mfma_f32_16x16x32_bf16( \
              af[ii][kk], arr[jj][kk], acc[(ah) * 4 + ii][(bh) * 2 + jj], 0, 0, 0); \
    __builtin_amdgcn_s_setprio(0); \
  } while (0)
#define BAR() do { asm volatile("" ::: "memory"); __builtin_amdgcn_s_barrier(); asm volatile("" ::: "memory"); } while (0)
#define VMW(n) do { asm volatile("s_waitcnt vmcnt(" #n ")" ::: "memory"); __builtin_amdgcn_sched_barrier(0); } while (0)
#define LGKM() do { asm volatile("s_waitcnt lgkmcnt(0)" ::: "memory"); __builtin_amdgcn_sched_barrier(0); } while (0)

  // ---- prologue: B kt0->buf0, B kt1->buf1 (gload); A kt0/kt1 via reg-transform
  BSTG(0, 0); BSTG(1, 1);
  QLOAD(0); QWRITE(0);
  QLOAD(1); QWRITE(1);
  LGKM();
  VMW(4);            // kt0's 4 B-loads retired; kt1's may float
  BAR();

  // ---- main: pairs (kt,kt+1); buf0=even, buf1=odd
  #pragma unroll
  for (int it = 0; it < 3; ++it) {
    const int kt = it * 2;
    // P1
    LDA8(0, 0); LDB4(0, 0, b0); QLOAD(kt + 2);
    BAR(); MFMAQ(0, 0, b0); BAR();
    // P2
    LDB4(0, 1, b1);
    BAR(); MFMAQ(0, 1, b1); BAR();
    // P3: B-buf0 fully read -> stage B-buf0(kt+2)
    LDA8(0, 1); BSTG(0, kt + 2);
    BAR(); MFMAQ(1, 1, b1); BAR();
    // P4: A-buf0 fully read -> transform+write A-buf0(kt+2)
    QWRITE(0);
    LGKM(); BAR(); MFMAQ(1, 0, b0); VMW(4); BAR();
    // P5
    LDA8(1, 0); LDB4(1, 0, b0); QLOAD(kt + 3);
    BAR(); MFMAQ(0, 0, b0); BAR();
    // P6
    LDB4(1, 1, b1);
    BAR(); MFMAQ(0, 1, b1); BAR();
    // P7: stage B-buf1(kt+3)
    LDA8(1, 1); BSTG(1, kt + 3);
    BAR(); MFMAQ(1, 1, b1); BAR();
    // P8: transform+write A-buf1(kt+3)
    QWRITE(1);
    LGKM(); BAR(); MFMAQ(1, 0, b0); VMW(4); BAR();
  }

  // ---- epilogue: kt=6 (buf0), kt=7 (buf1); nothing left to stage
  LDA8(0, 0); LDB4(0, 0, b0);
  BAR(); MFMAQ(0, 0, b0); BAR();
  LDB4(0, 1, b1);
  BAR(); MFMAQ(0, 1, b1); BAR();
  LDA8(0, 1);
  BAR(); MFMAQ(1, 1, b1); BAR();
  MFMAQ(1, 0, b0); VMW(0); BAR();
  LDA8(1, 0); LDB4(1, 0, b0);
  BAR(); MFMAQ(0, 0, b0); BAR();
  LDB4(1, 1, b1);
  BAR(); MFMAQ(0, 1, b1); BAR();
  LDA8(1, 1);
  BAR(); MFMAQ(1, 1, b1); BAR();
  MFMAQ(1, 0, b0);

  // ---- C write f32
  #pragma unroll
  for (int i = 0; i < 8; i++)
    #pragma unroll
    for (int j2 = 0; j2 < 4; j2++) {
      int row = m0 + wm + i * 16 + quad * 4;
      int col = n0 + wn + j2 * 16 + r;
      #pragma unroll
      for (int p = 0; p < 4; p++)
        Cv[(size_t)(row + p) * 512 + col] = acc[i][j2][p];
    }
#undef BSTG
#undef QLOAD
#undef PH
#undef QWRITE
#undef LDA8
#undef LDB4
#undef MFMAQ
#undef BAR
#undef VMW
#undef LGKM
}

extern "C" void kernel_launch(void* const* d_in, const int* in_sizes, int n_in,
                              void* d_out, int out_size, void* d_ws, size_t ws_size,
                              hipStream_t stream) {
  const float* x = (const float*)d_in[0];
  const float* norm_w = (const float*)d_in[1];
  const float* wq = (const float*)d_in[2];
  const float* wk = (const float*)d_in[3];
  const float* wv = (const float*)d_in[4];
  const float* wo = (const float*)d_in[5];
  float* out = (float*)d_out;

  char* ws = (char*)d_ws;
  unsigned short* xn  = (unsigned short*)(ws);                  // 33,554,432 B
  unsigned short* Wb  = (unsigned short*)(ws + 33554432);       //  1,048,576 B
  unsigned short* wob = (unsigned short*)(ws + 34603008);       //    524,288 B
  unsigned short* qkv = (unsigned short*)(ws + 35127296);       // 33,554,432 B (Q only, stride 512)
  float2* rope        = (float2*)(ws + 102236160);              //  2,097,152 B
  float* KV           = (float*)(ws + 104333312);               //      4,096 B
  float* Ksum         = (float*)(ws + 104337408);               //      4,096 B

  static bool s_attr = false;
  if (!s_attr) {
    (void)hipFuncSetAttribute(reinterpret_cast<const void*>(&k_gemm256<true, true>),
                              hipFuncAttributeMaxDynamicSharedMemorySize, 131072);
    (void)hipFuncSetAttribute(reinterpret_cast<const void*>(&k_gemm2q),
                              hipFuncAttributeMaxDynamicSharedMemorySize, 131072);
    s_attr = true;
  }

  k_prep<<<4096, 256, 0, stream>>>(x, norm_w, wq, wk, wv, wo, Wb, wob, rope, KV, xn);
  k_gemm256<true, true><<<dim3(128, 4), 512, 131072, stream>>>(
      xn, Wb, (void*)qkv, 512, rope, KV, Ksum);
  k_gemm2q<<<dim3(128, 2), 512, 131072, stream>>>(
      qkv, wob, out, (const float*)rope, KV, Ksum);
}